// Round 1
// baseline (73.818 us; speedup 1.0000x reference)
//
#include <hip/hip_runtime.h>
#include <math.h>

// Cox partial-likelihood loss, N = 8192 (fixed by harness).
//
// risk_sum[i] = sum_j exp(theta[j]) * (survtime[j] >= survtime[i])
// loss = -mean((theta - log(risk_sum)) * censor)
//
// Strategy: O(N^2) brute force is only ~67M VALU ops -> a few us on 256 CUs.
// 256 blocks x 1024 threads. Each block:
//   - stages exp(theta[]) and survtime[] into LDS (2 x 32KB = 64KB exactly)
//   - handles 32 rows i; threads = 32 i-lanes x 32 j-partitions
//     (p = tid>>5 so each 32-lane group broadcasts one LDS address;
//      <=2 distinct addrs per wave64 -> 2-way aliasing, free per m136)
//   - float4 LDS reads, conditional accumulate, LDS+shuffle reduction
//   - one atomicAdd per block + device-scope ticket; last block writes
//     -total/N to d_out (single kernel launch, no finalize kernel).

#define T_BLK 1024
#define I_PER_BLK 32
#define NP 32          // j partitions per block (= T_BLK / I_PER_BLK)

__global__ __launch_bounds__(T_BLK) void cox_loss_kernel(
    const float* __restrict__ theta,      // hazard_pred, n floats
    const float* __restrict__ survtime,   // n floats
    const float* __restrict__ censor,     // n floats
    float* __restrict__ out,              // 1 float
    float* __restrict__ acc,              // ws[0], pre-zeroed
    unsigned int* __restrict__ ticket,    // ws[1], pre-zeroed
    int n, int nblocks)
{
    __shared__ float s_exp[8192];
    __shared__ float s_time[8192];

    const int tid = threadIdx.x;

    // ---- stage inputs into LDS, vectorized ----
    const int nvec = n >> 2;
    const float4* th4 = (const float4*)theta;
    const float4* st4 = (const float4*)survtime;
    for (int v = tid; v < nvec; v += T_BLK) {
        float4 t = th4[v];
        float4 s = st4[v];
        int j = v << 2;
        s_exp[j + 0] = expf(t.x);
        s_exp[j + 1] = expf(t.y);
        s_exp[j + 2] = expf(t.z);
        s_exp[j + 3] = expf(t.w);
        s_time[j + 0] = s.x;
        s_time[j + 1] = s.y;
        s_time[j + 2] = s.z;
        s_time[j + 3] = s.w;
    }
    __syncthreads();

    // ---- per-thread partial risk sum for row i over j-partition p ----
    const int i_local = tid & (I_PER_BLK - 1);
    const int p       = tid >> 5;                  // 0..31
    const int i       = blockIdx.x * I_PER_BLK + i_local;
    const float ti    = s_time[i];

    const int ch = n / NP;                         // 256 js per partition
    const float4* e4 = (const float4*)(s_exp + p * ch);
    const float4* t4 = (const float4*)(s_time + p * ch);
    float sum = 0.0f;
    #pragma unroll 4
    for (int k = 0; k < ch / 4; ++k) {
        float4 e = e4[k];
        float4 s = t4[k];
        sum += (s.x >= ti) ? e.x : 0.0f;
        sum += (s.y >= ti) ? e.y : 0.0f;
        sum += (s.z >= ti) ? e.z : 0.0f;
        sum += (s.w >= ti) ? e.w : 0.0f;
    }

    // ---- reduce 32 partials per row (reuse s_exp as scratch) ----
    __syncthreads();
    s_exp[tid] = sum;            // index = p*32 + i_local
    __syncthreads();

    if (tid < I_PER_BLK) {
        float rs = 0.0f;
        #pragma unroll
        for (int q = 0; q < NP; ++q)
            rs += s_exp[q * I_PER_BLK + tid];   // lane t hits bank t: conflict-free

        float contrib = (theta[i] - logf(rs)) * censor[i];

        // reduce 32 row contributions within wave 0
        #pragma unroll
        for (int off = 16; off > 0; off >>= 1)
            contrib += __shfl_down(contrib, off);

        if (tid == 0) {
            atomicAdd(acc, contrib);
            __threadfence();
            unsigned int old = atomicAdd(ticket, 1u);
            if (old == (unsigned int)(nblocks - 1)) {
                // all blocks' acc adds happened-before their ticket adds;
                // atomic RMW read is device-scope coherent across XCDs
                float total = atomicAdd(acc, 0.0f);
                out[0] = -total / (float)n;
            }
        }
    }
}

extern "C" void kernel_launch(void* const* d_in, const int* in_sizes, int n_in,
                              void* d_out, int out_size, void* d_ws, size_t ws_size,
                              hipStream_t stream) {
    const float* theta    = (const float*)d_in[0];  // hazard_pred (N,1) flat
    const float* survtime = (const float*)d_in[1];
    const float* censor   = (const float*)d_in[2];
    float* out = (float*)d_out;

    const int n = in_sizes[1];                      // 8192

    float* acc            = (float*)d_ws;
    unsigned int* ticket  = (unsigned int*)((char*)d_ws + sizeof(float));

    // ws is re-poisoned to 0xAA before every timed launch: zero acc+ticket.
    hipMemsetAsync(d_ws, 0, 2 * sizeof(float), stream);

    const int nblocks = n / I_PER_BLK;              // 256
    cox_loss_kernel<<<nblocks, T_BLK, 0, stream>>>(
        theta, survtime, censor, out, acc, ticket, n, nblocks);
}

// Round 2
// 65.518 us; speedup vs baseline: 1.1267x; 1.1267x over previous
//
#include <hip/hip_runtime.h>
#include <math.h>

// Cox partial-likelihood loss, N = 8192 (fixed by harness).
//
// risk_sum[i] = sum_j exp(theta[j]) * (survtime[j] >= survtime[i])
// loss = -mean((theta - log(risk_sum)) * censor)
//
// Round-2 design (register-tiled):
//   256 blocks x 1024 threads, 32 rows per block.
//   Threads split as (row-group ig = tid&3, j-partition p = tid>>2):
//     each thread owns 8 rows (ti[8]/acc[8] in registers) and 32 j's.
//   Each (e_j, t_j) float4 is read from LDS ONCE and feeds 8 accumulators
//   -> LDS traffic /8 vs round-1 (512 MB -> 64 MB), VALU-bound at ~2.6 us.
//   8 independent accumulator chains give ILP (round-1 had 1 serial chain).
//   Two-stage LDS reduction -> per-block partial plain-stored to ws[b]
//   (overwrites 0xAA poison, no memset needed), tiny finalize kernel sums
//   256 partials. Deterministic, no atomics, no in-graph memset dispatch.
//
// Fixed floor: harness re-poisons the ~256 MB ws with fillBufferAligned
// (~39.5 us @ 6.8 TB/s) inside the timed region — not controllable here.

#define TBLK 1024
#define ROWS_PER_BLK 32      // 8192 / 256 blocks
#define RPT 8                // rows per thread (register tile)
#define JP 32                // j's per thread partition (8192 / 256 partitions)

__global__ __launch_bounds__(TBLK) void cox_main(
    const float* __restrict__ theta,
    const float* __restrict__ survtime,
    const float* __restrict__ censor,
    float* __restrict__ block_partials,   // ws, one float per block
    int n)
{
    __shared__ float s_exp[8192];
    __shared__ float s_time[8192];

    const int tid = threadIdx.x;
    const int b   = blockIdx.x;

    // ---- stage all of exp(theta[]) and survtime[] into LDS ----
    const float4* th4 = (const float4*)theta;
    const float4* st4 = (const float4*)survtime;
    for (int v = tid; v < (n >> 2); v += TBLK) {
        float4 t = th4[v];
        float4 s = st4[v];
        int j = v << 2;
        s_exp[j + 0] = expf(t.x);
        s_exp[j + 1] = expf(t.y);
        s_exp[j + 2] = expf(t.z);
        s_exp[j + 3] = expf(t.w);
        s_time[j + 0] = s.x;
        s_time[j + 1] = s.y;
        s_time[j + 2] = s.z;
        s_time[j + 3] = s.w;
    }
    __syncthreads();

    // ---- register-tiled pair loop ----
    const int ig    = tid & 3;        // row group 0..3
    const int p     = tid >> 2;       // j partition 0..255
    const int row0  = ig * RPT;       // 0,8,16,24 within block's 32 rows
    const int ibase = b * ROWS_PER_BLK;

    float ti[RPT], acc[RPT];
    #pragma unroll
    for (int r = 0; r < RPT; ++r) {
        ti[r]  = s_time[ibase + row0 + r];
        acc[r] = 0.0f;
    }

    const float4* e4 = (const float4*)s_exp  + p * (JP / 4);   // 8 float4 per partition
    const float4* t4 = (const float4*)s_time + p * (JP / 4);
    #pragma unroll
    for (int k = 0; k < JP / 4; ++k) {
        float4 e = e4[k];
        float4 t = t4[k];
        #pragma unroll
        for (int r = 0; r < RPT; ++r) {
            float tr = ti[r];
            acc[r] += (t.x >= tr) ? e.x : 0.0f;
            acc[r] += (t.y >= tr) ? e.y : 0.0f;
            acc[r] += (t.z >= tr) ? e.z : 0.0f;
            acc[r] += (t.w >= tr) ? e.w : 0.0f;
        }
    }

    // ---- reduce 256 partials per row ----
    __syncthreads();                  // done with s_exp contents
    // s_red = s_exp reinterpreted as [256 partitions][32 rows]
    #pragma unroll
    for (int r = 0; r < RPT; ++r)
        s_exp[p * ROWS_PER_BLK + row0 + r] = acc[r];
    __syncthreads();

    // stage 2: 1024 threads fold 256 partials -> 32 per row
    {
        const int il = tid & 31;      // row
        const int q  = tid >> 5;      // 0..31
        float s = 0.0f;
        #pragma unroll
        for (int m = 0; m < 8; ++m)
            s += s_exp[(q * 8 + m) * ROWS_PER_BLK + il];
        s_time[q * ROWS_PER_BLK + il] = s;   // reuse s_time as scratch
    }
    __syncthreads();

    // stage 3: threads 0..31 finish their row, then lane-reduce the block
    if (tid < ROWS_PER_BLK) {
        float rs = 0.0f;
        #pragma unroll
        for (int q = 0; q < 32; ++q)
            rs += s_time[q * ROWS_PER_BLK + tid];   // bank = tid: conflict-free

        const int i = ibase + tid;
        float contrib = (theta[i] - logf(rs)) * censor[i];

        #pragma unroll
        for (int off = 16; off > 0; off >>= 1)
            contrib += __shfl_down(contrib, off);

        if (tid == 0)
            block_partials[b] = contrib;    // plain store, overwrites poison
    }
}

__global__ __launch_bounds__(256) void cox_finalize(
    const float* __restrict__ partials,
    float* __restrict__ out,
    int nblocks, int n)
{
    const int t = threadIdx.x;
    float v = (t < nblocks) ? partials[t] : 0.0f;
    #pragma unroll
    for (int off = 32; off > 0; off >>= 1)
        v += __shfl_down(v, off);

    __shared__ float s[4];
    if ((t & 63) == 0) s[t >> 6] = v;
    __syncthreads();
    if (t == 0)
        out[0] = -(s[0] + s[1] + s[2] + s[3]) / (float)n;
}

extern "C" void kernel_launch(void* const* d_in, const int* in_sizes, int n_in,
                              void* d_out, int out_size, void* d_ws, size_t ws_size,
                              hipStream_t stream) {
    const float* theta    = (const float*)d_in[0];  // hazard_pred (N,1) flat
    const float* survtime = (const float*)d_in[1];
    const float* censor   = (const float*)d_in[2];
    float* out = (float*)d_out;

    const int n = in_sizes[1];                      // 8192
    const int nblocks = n / ROWS_PER_BLK;           // 256

    float* block_partials = (float*)d_ws;           // no init needed: plain stores

    cox_main<<<nblocks, TBLK, 0, stream>>>(theta, survtime, censor,
                                           block_partials, n);
    cox_finalize<<<1, 256, 0, stream>>>(block_partials, out, nblocks, n);
}